// Round 3
// baseline (397.620 us; speedup 1.0000x reference)
//
#include <hip/hip_runtime.h>
#include <hip/hip_bf16.h>
#include <stdint.h>

#define NN 4096
#define NF 128
#define NB 4

typedef __attribute__((ext_vector_type(4))) float  floatx4;
typedef __attribute__((ext_vector_type(8))) __bf16 bf16x8;

// ---------------------------------------------------------------------------
// Prep: Xpack[b][kc][f][k8] = bf16(X[b][kc*32+k8][f]), via LDS transpose.
//       wpack[kc2][n][k8]   = bf16(w[kc2*32+k8][n]).
// v3: global loads vectorized to float4 (G13); Xs pad 132 keeps 16B align.
// ---------------------------------------------------------------------------
__global__ __launch_bounds__(256) void prep_kernel(const float* __restrict__ X,
                                                   const float* __restrict__ w,
                                                   __bf16* __restrict__ Xpack,
                                                   __bf16* __restrict__ wpack) {
    __shared__ float Xs[32][132];
    const int tid = threadIdx.x;
    const int bx  = blockIdx.x;
    if (bx == 512) {  // wpack: tiny
        for (int p = tid; p < 512; p += 256) {
            int kc = p >> 7, n = p & 127;
#pragma unroll
            for (int k8 = 0; k8 < 32; k8 += 8) {
                bf16x8 v;
#pragma unroll
                for (int j = 0; j < 8; j++)
                    v[j] = (__bf16)w[(size_t)(kc * 32 + k8 + j) * NF + n];
                *(bf16x8*)(wpack + ((size_t)(kc * 128 + n)) * 32 + k8) = v;
            }
        }
        return;
    }
    const int b  = bx >> 7;
    const int kc = bx & 127;
    const float* Xt = X + ((size_t)b * NN + (size_t)kc * 32) * NF;
#pragma unroll
    for (int j = 0; j < 4; j++) {
        int p = tid + j * 256;                     // float4 index, 1024 total
        floatx4 v = *(const floatx4*)(Xt + (size_t)p * 4);
        *(floatx4*)&Xs[p >> 5][(p & 31) * 4] = v;  // row p>>5, col (p&31)*4
    }
    __syncthreads();
    const int f  = tid >> 1;
    const int kh = (tid & 1) * 16;
    bf16x8 v0, v1;
#pragma unroll
    for (int j = 0; j < 8; j++) v0[j] = (__bf16)Xs[kh + j][f];
#pragma unroll
    for (int j = 0; j < 8; j++) v1[j] = (__bf16)Xs[kh + 8 + j][f];
    __bf16* op = Xpack + (((size_t)b * 128 + kc) * 128 + f) * 32 + kh;
    *(bf16x8*)op = v0;
    *(bf16x8*)(op + 8) = v1;
}

// ---------------------------------------------------------------------------
// Main v3: register streaming, unroll-2 ping-pong (no register rotations).
// Grid = 512 blocks (XCD-swizzled) x 256 thr; block = 32 rows, 4 waves =
// 4 k-quarters (32 chunks of K=32 each). 2 blocks/CU, 8 waves/CU.
// Per k-step: consume A(k)/B(k) from its slot, issue B(k+1) into the other
// B slot, A(k+2) back into the same A slot (freed by the cvt). vmcnt FIFO at
// the MFMA leaves {A(k+1), B(k+1), A(k+2)} in flight (~16KB/wave).
// ---------------------------------------------------------------------------
__global__ __launch_bounds__(256, 2) void main_kernel(const float* __restrict__ A,
                                                      const float* __restrict__ X,
                                                      const __bf16* __restrict__ Xpack,
                                                      const __bf16* __restrict__ wpack,
                                                      float* __restrict__ out) {
    __shared__ float  Pacc[3][32][132];  // waves 1..3 partial acc
    __shared__ float  degp[4][32];       // per-wave partial row-sums
    __shared__ __bf16 Us[32][136];       // u in bf16 for second GEMM

    const int tid  = threadIdx.x;
    const int kq   = tid >> 6;       // wave = k-quarter
    const int lane = tid & 63;
    const int lm   = lane & 15;
    const int quad = lane >> 4;

    // bijective XCD swizzle: nwg=512 (%8==0); each XCD gets 64 consecutive
    // tiles (same b, contiguous m) -> Xpack[b] (1MB) L2-resident per XCD
    const int bid = blockIdx.x;
    const int swz = (bid & 7) * 64 + (bid >> 3);
    const int b   = swz >> 7;
    const int m0  = (swz & 127) << 5;

    const float* Ap0 = A + ((size_t)b * NN + m0 + lm) * NN + kq * 1024 + quad * 8;
    const __bf16* Bp = Xpack + ((size_t)(b * 128 + kq * 32)) * 4096 + lm * 32 + quad * 8;

    floatx4 acc[2][8];
#pragma unroll
    for (int s = 0; s < 2; s++)
#pragma unroll
        for (int nt = 0; nt < 8; nt++) acc[s][nt] = (floatx4){0.f, 0.f, 0.f, 0.f};
    floatx4 sum0 = {0.f, 0.f, 0.f, 0.f}, sum1 = {0.f, 0.f, 0.f, 0.f};

    // ping-pong slots: a*[0..1] = row lm (lo,hi 16B), a*[2..3] = row lm+16
    floatx4 aE[4], aO[4];
    bf16x8  bE[8], bO[8];

    // prologue order A(0), B(0), A(1): forcing B(0) keeps A(1) in flight
#pragma unroll
    for (int h = 0; h < 2; h++) {
        const float* p = Ap0 + (size_t)h * 16 * NN;
        aE[2 * h]     = __builtin_nontemporal_load((const floatx4*)p);
        aE[2 * h + 1] = __builtin_nontemporal_load((const floatx4*)(p + 4));
    }
#pragma unroll
    for (int nt = 0; nt < 8; nt++) bE[nt] = *(const bf16x8*)(Bp + nt * 512);
#pragma unroll
    for (int h = 0; h < 2; h++) {
        const float* p = Ap0 + (size_t)h * 16 * NN + 32;
        aO[2 * h]     = __builtin_nontemporal_load((const floatx4*)p);
        aO[2 * h + 1] = __builtin_nontemporal_load((const floatx4*)(p + 4));
    }

#define STEP(AC, BC, BN, KB, KA)                                              \
    {                                                                         \
        /* consume A slot (frees it), row-sums */                             \
        sum0 += AC[0] + AC[1];                                                \
        sum1 += AC[2] + AC[3];                                                \
        bf16x8 af0, af1;                                                      \
        _Pragma("unroll")                                                     \
        for (int i = 0; i < 4; i++) {                                         \
            af0[i] = (__bf16)AC[0][i]; af0[4 + i] = (__bf16)AC[1][i];         \
            af1[i] = (__bf16)AC[2][i]; af1[4 + i] = (__bf16)AC[3][i];         \
        }                                                                     \
        /* issue next B, then next-next A (FIFO order) */                     \
        const int kb_ = (KB) < 32 ? (KB) : 0;                                 \
        const int ka_ = (KA) < 32 ? (KA) : 0;                                 \
        const __bf16* Bf_ = Bp + (size_t)kb_ * 4096;                          \
        _Pragma("unroll")                                                     \
        for (int nt = 0; nt < 8; nt++) BN[nt] = *(const bf16x8*)(Bf_ + nt * 512); \
        _Pragma("unroll")                                                     \
        for (int h = 0; h < 2; h++) {                                         \
            const float* An_ = Ap0 + (size_t)h * 16 * NN + (size_t)ka_ * 32;  \
            AC[2 * h]     = __builtin_nontemporal_load((const floatx4*)An_);  \
            AC[2 * h + 1] = __builtin_nontemporal_load((const floatx4*)(An_ + 4)); \
        }                                                                     \
        /* MFMA on current B slot */                                          \
        _Pragma("unroll")                                                     \
        for (int nt = 0; nt < 8; nt++) {                                      \
            acc[0][nt] = __builtin_amdgcn_mfma_f32_16x16x32_bf16(af0, BC[nt], acc[0][nt], 0, 0, 0); \
            acc[1][nt] = __builtin_amdgcn_mfma_f32_16x16x32_bf16(af1, BC[nt], acc[1][nt], 0, 0, 0); \
        }                                                                     \
    }

    for (int kc = 0; kc < 32; kc += 2) {
        STEP(aE, bE, bO, kc + 1, kc + 2);
        STEP(aO, bO, bE, kc + 2, kc + 3);
    }
#undef STEP

    // per-row k-quarter sums: combine quad phases (each quad holds 8 k/chunk)
    float ds0 = sum0[0] + sum0[1] + sum0[2] + sum0[3];
    float ds1 = sum1[0] + sum1[1] + sum1[2] + sum1[3];
    ds0 += __shfl_xor(ds0, 16, 64); ds0 += __shfl_xor(ds0, 32, 64);
    ds1 += __shfl_xor(ds1, 16, 64); ds1 += __shfl_xor(ds1, 32, 64);
    if (quad == 0) { degp[kq][lm] = ds0; degp[kq][16 + lm] = ds1; }

    if (kq) {
#pragma unroll
        for (int s = 0; s < 2; s++)
#pragma unroll
            for (int nt = 0; nt < 8; nt++)
#pragma unroll
                for (int i = 0; i < 4; i++)
                    Pacc[kq - 1][s * 16 + quad * 4 + i][nt * 16 + lm] = acc[s][nt][i];
    }

    // w B-frags (global, independent of LDS) — issue before the barrier
    bf16x8 wf[4][2];
#pragma unroll
    for (int kc2 = 0; kc2 < 4; kc2++)
#pragma unroll
        for (int nt = 0; nt < 2; nt++)
            wf[kc2][nt] = *(const bf16x8*)(wpack +
                (size_t)(kc2 * 128 + kq * 32 + nt * 16 + lm) * 32 + quad * 8);

    __syncthreads();

    if (kq == 0) {
        float degv[2][4];
#pragma unroll
        for (int s = 0; s < 2; s++)
#pragma unroll
            for (int i = 0; i < 4; i++) {
                int r = s * 16 + quad * 4 + i;
                degv[s][i] = degp[0][r] + degp[1][r] + degp[2][r] + degp[3][r] + 1.0f;
            }
        const float* Xb = X + ((size_t)b * NN + m0) * NF;
#pragma unroll
        for (int s = 0; s < 2; s++)
#pragma unroll
            for (int nt = 0; nt < 8; nt++)
#pragma unroll
                for (int i = 0; i < 4; i++) {
                    int r = s * 16 + quad * 4 + i, col = nt * 16 + lm;
                    float u = acc[s][nt][i] + Pacc[0][r][col] + Pacc[1][r][col] +
                              Pacc[2][r][col] + Xb[(size_t)r * NF + col];
                    Us[r][col] = (__bf16)(u / degv[s][i]);
                }
    }
    __syncthreads();

    // z = u @ w (K=128); wave kq: all 32 rows x cols [kq*32, +32)
    float* ob = out + ((size_t)b * NN + m0) * NF;
#pragma unroll
    for (int s = 0; s < 2; s++) {
        floatx4 z0 = {0.f, 0.f, 0.f, 0.f};
        floatx4 z1 = {0.f, 0.f, 0.f, 0.f};
#pragma unroll
        for (int kc2 = 0; kc2 < 4; kc2++) {
            bf16x8 ua = *(const bf16x8*)&Us[s * 16 + lm][kc2 * 32 + quad * 8];
            z0 = __builtin_amdgcn_mfma_f32_16x16x32_bf16(ua, wf[kc2][0], z0, 0, 0, 0);
            z1 = __builtin_amdgcn_mfma_f32_16x16x32_bf16(ua, wf[kc2][1], z1, 0, 0, 0);
        }
#pragma unroll
        for (int nt = 0; nt < 2; nt++) {
            int col = kq * 32 + nt * 16 + lm;
            floatx4 zv = nt ? z1 : z0;
#pragma unroll
            for (int i = 0; i < 4; i++) {
                int r = s * 16 + quad * 4 + i;
                float v = zv[i];
                ob[(size_t)r * NF + col] = v > 0.f ? v : 0.f;
            }
        }
    }
}

extern "C" void kernel_launch(void* const* d_in, const int* in_sizes, int n_in,
                              void* d_out, int out_size, void* d_ws, size_t ws_size,
                              hipStream_t stream) {
    const float* A = (const float*)d_in[0];  // [4,4096,4096]
    const float* X = (const float*)d_in[1];  // [4,4096,128]
    const float* w = (const float*)d_in[2];  // [128,128]
    float* out = (float*)d_out;              // [4,4096,128]

    __bf16* Xpack = (__bf16*)d_ws;                 // 4 MB
    __bf16* wpack = Xpack + (size_t)NB * NF * NN;  // +32 KB

    prep_kernel<<<513, 256, 0, stream>>>(X, w, Xpack, wpack);
    main_kernel<<<512, 256, 0, stream>>>(A, X, Xpack, wpack, out);
}